// Round 1
// baseline (1556.923 us; speedup 1.0000x reference)
//
#include <hip/hip_runtime.h>
#include <math.h>

#define Bc 8
#define Nseq 512
#define DM 512
#define Hh 8
#define DKc 64
#define DVc 64
#define NUMREL 1023
#define ZOFF 511   // NUMREL/2

// ---------------------------------------------------------------------------
// Tiled fp32 GEMM: C = A[M,K] @ W[K,N] + bias[N]
// OUT_MODE 0: C row-major [M,N]
// OUT_MODE 1: QKV layout — row m=(b*Nseq+i), col c=(h*64+d) -> [((b*H+h)*Nseq+i)*64+d]
// ---------------------------------------------------------------------------
template <int OUT_MODE>
__global__ __launch_bounds__(256) void gemm_bias(const float* __restrict__ A,
                                                 const float* __restrict__ W,
                                                 const float* __restrict__ bias,
                                                 float* __restrict__ C,
                                                 int M, int N, int K) {
  const int bm = blockIdx.y * 64;
  const int bn = blockIdx.x * 64;
  const int tid = threadIdx.x;
  const int tx = tid & 15;   // 0..15 -> 4 cols each
  const int ty = tid >> 4;   // 0..15 -> 4 rows each

  __shared__ float As[16][64];      // As[k][m]
  __shared__ float Bs[16][64];      // Bs[k][n]

  float acc[4][4] = {};

  for (int kk = 0; kk < K; kk += 16) {
#pragma unroll
    for (int l = tid; l < 1024; l += 256) {
      int m = l >> 4, k = l & 15;
      As[k][m] = A[(bm + m) * K + kk + k];
    }
#pragma unroll
    for (int l = tid; l < 1024; l += 256) {
      int k = l >> 6, n = l & 63;
      Bs[k][n] = W[(kk + k) * N + bn + n];
    }
    __syncthreads();
#pragma unroll
    for (int k = 0; k < 16; ++k) {
      float a[4], b[4];
#pragma unroll
      for (int i = 0; i < 4; ++i) a[i] = As[k][ty * 4 + i];
#pragma unroll
      for (int j = 0; j < 4; ++j) b[j] = Bs[k][tx * 4 + j];
#pragma unroll
      for (int i = 0; i < 4; ++i)
#pragma unroll
        for (int j = 0; j < 4; ++j) acc[i][j] += a[i] * b[j];
    }
    __syncthreads();
  }

#pragma unroll
  for (int i = 0; i < 4; ++i) {
    int m = bm + ty * 4 + i;
#pragma unroll
    for (int j = 0; j < 4; ++j) {
      int c = bn + tx * 4 + j;
      float v = acc[i][j] + bias[c];
      if (OUT_MODE == 0) {
        C[(size_t)m * N + c] = v;
      } else {
        int b = m / Nseq, iseq = m % Nseq;
        int h = c >> 6, d = c & 63;
        C[(((size_t)(b * Hh + h)) * Nseq + iseq) * 64 + d] = v;
      }
    }
  }
}

// ---------------------------------------------------------------------------
// Attention: one block per (b,h,i). Scores in LDS, LDS-tree softmax,
// folded (V + P_v) accumulation. Output layout [B, N, H*DV].
// ---------------------------------------------------------------------------
__global__ __launch_bounds__(256) void attn_kernel(const float* __restrict__ Qw,
                                                   const float* __restrict__ Kw,
                                                   const float* __restrict__ Vw,
                                                   const float* __restrict__ Pk,
                                                   const float* __restrict__ Pv,
                                                   float* __restrict__ Ow) {
  const int iq = blockIdx.x;
  const int h = blockIdx.y;
  const int b = blockIdx.z;
  const int tid = threadIdx.x;

  __shared__ float q[64];
  __shared__ float sc[Nseq];
  __shared__ float red[256];

  const size_t bh = (size_t)(b * Hh + h) * Nseq;
  const float* Qp = Qw + (bh + iq) * 64;
  const float* Kp = Kw + bh * 64;
  const float* Vp = Vw + bh * 64;

  if (tid < 64) q[tid] = Qp[tid];
  __syncthreads();

  // scores
  float lmax = -INFINITY;
  for (int j = tid; j < Nseq; j += 256) {
    const float* kr = Kp + j * 64;
    float s = 0.f;
#pragma unroll
    for (int d = 0; d < 64; ++d) s += q[d] * kr[d];
    s = (s + Pk[(size_t)(ZOFF + j - iq) * Hh + h]) * 0.125f;
    sc[j] = s;
    lmax = fmaxf(lmax, s);
  }
  red[tid] = lmax;
  __syncthreads();
#pragma unroll
  for (int off = 128; off > 0; off >>= 1) {
    if (tid < off) red[tid] = fmaxf(red[tid], red[tid + off]);
    __syncthreads();
  }
  const float mx = red[0];
  __syncthreads();

  // exp + sum
  float lsum = 0.f;
  for (int j = tid; j < Nseq; j += 256) {
    float e = __expf(sc[j] - mx);
    sc[j] = e;
    lsum += e;
  }
  red[tid] = lsum;
  __syncthreads();
#pragma unroll
  for (int off = 128; off > 0; off >>= 1) {
    if (tid < off) red[tid] += red[tid + off];
    __syncthreads();
  }
  const float inv = 1.f / red[0];
  __syncthreads();

  // out[d] = inv * sum_j p_j * (V[j,d] + P_v[rel(iq,j),h,d])
  const int d = tid & 63;
  const int chunk = tid >> 6;  // 0..3, 128 j's each
  float acc = 0.f;
  const int j0 = chunk * 128;
  for (int j = j0; j < j0 + 128; ++j) {
    float p = sc[j];
    acc += p * (Vp[j * 64 + d] + Pv[((size_t)(ZOFF + j - iq) * Hh + h) * 64 + d]);
  }
  red[tid] = acc;
  __syncthreads();
  if (tid < 64) {
    float o = (red[tid] + red[64 + tid] + red[128 + tid] + red[192 + tid]) * inv;
    Ow[((size_t)(b * Nseq + iq)) * (Hh * DVc) + h * 64 + tid] = o;
  }
}

// ---------------------------------------------------------------------------
extern "C" void kernel_launch(void* const* d_in, const int* in_sizes, int n_in,
                              void* d_out, int out_size, void* d_ws, size_t ws_size,
                              hipStream_t stream) {
  const float* X  = (const float*)d_in[0];
  const float* Wq = (const float*)d_in[1];
  const float* bq = (const float*)d_in[2];
  const float* Wk = (const float*)d_in[3];
  const float* bk = (const float*)d_in[4];
  const float* Wv = (const float*)d_in[5];
  const float* bv = (const float*)d_in[6];
  const float* Wo = (const float*)d_in[7];
  const float* bo = (const float*)d_in[8];
  const float* Pk = (const float*)d_in[9];
  const float* Pv = (const float*)d_in[10];
  float* out = (float*)d_out;

  const int M = Bc * Nseq;            // 4096
  const size_t per = (size_t)Bc * Hh * Nseq * 64;  // 2,097,152 floats
  float* Qw = (float*)d_ws;
  float* Kw = Qw + per;
  float* Vw = Kw + per;
  float* Aw = Vw + per;               // attention out [B, N, H*DV]

  dim3 gGemm(DM / 64, M / 64);        // (8, 64)
  dim3 blk(256);

  gemm_bias<1><<<gGemm, blk, 0, stream>>>(X, Wq, bq, Qw, M, Hh * DKc, DM);
  gemm_bias<1><<<gGemm, blk, 0, stream>>>(X, Wk, bk, Kw, M, Hh * DKc, DM);
  gemm_bias<1><<<gGemm, blk, 0, stream>>>(X, Wv, bv, Vw, M, Hh * DVc, DM);

  dim3 gAttn(Nseq, Hh, Bc);
  attn_kernel<<<gAttn, blk, 0, stream>>>(Qw, Kw, Vw, Pk, Pv, Aw);

  gemm_bias<0><<<gGemm, blk, 0, stream>>>(Aw, Wo, bo, out, M, DM, Hh * DVc);
}

// Round 2
// 449.508 us; speedup vs baseline: 3.4636x; 3.4636x over previous
//
#include <hip/hip_runtime.h>
#include <math.h>

#define Bc 8
#define Nseq 512
#define DM 512
#define Hh 8
#define NUMREL 1023
#define ZOFF 511   // NUMREL/2

typedef short bf16x8 __attribute__((ext_vector_type(8)));
typedef float f32x4 __attribute__((ext_vector_type(4)));

__device__ __forceinline__ unsigned short f2bf(float f) {
  unsigned u = __builtin_bit_cast(unsigned, f);
  u += 0x7fff + ((u >> 16) & 1);   // RNE
  return (unsigned short)(u >> 16);
}

__device__ __forceinline__ bf16x8 ld8_bf16(const float* __restrict__ p) {
  const float4 a = *(const float4*)p;
  const float4 b = *(const float4*)(p + 4);
  bf16x8 r;
  r[0] = (short)f2bf(a.x); r[1] = (short)f2bf(a.y);
  r[2] = (short)f2bf(a.z); r[3] = (short)f2bf(a.w);
  r[4] = (short)f2bf(b.x); r[5] = (short)f2bf(b.y);
  r[6] = (short)f2bf(b.z); r[7] = (short)f2bf(b.w);
  return r;
}

// ---------------------------------------------------------------------------
// Tiled fp32 GEMM: C = A[M,K] @ W[K,N] + bias[N]   (unchanged, known-good)
// OUT_MODE 0: C row-major [M,N]
// OUT_MODE 1: QKV layout — row m=(b*Nseq+i), col c=(h*64+d) -> [((b*H+h)*Nseq+i)*64+d]
// ---------------------------------------------------------------------------
template <int OUT_MODE>
__global__ __launch_bounds__(256) void gemm_bias(const float* __restrict__ A,
                                                 const float* __restrict__ W,
                                                 const float* __restrict__ bias,
                                                 float* __restrict__ C,
                                                 int M, int N, int K) {
  const int bm = blockIdx.y * 64;
  const int bn = blockIdx.x * 64;
  const int tid = threadIdx.x;
  const int tx = tid & 15;
  const int ty = tid >> 4;

  __shared__ float As[16][64];
  __shared__ float Bs[16][64];

  float acc[4][4] = {};

  for (int kk = 0; kk < K; kk += 16) {
#pragma unroll
    for (int l = tid; l < 1024; l += 256) {
      int m = l >> 4, k = l & 15;
      As[k][m] = A[(size_t)(bm + m) * K + kk + k];
    }
#pragma unroll
    for (int l = tid; l < 1024; l += 256) {
      int k = l >> 6, n = l & 63;
      Bs[k][n] = W[(size_t)(kk + k) * N + bn + n];
    }
    __syncthreads();
#pragma unroll
    for (int k = 0; k < 16; ++k) {
      float a[4], b[4];
#pragma unroll
      for (int i = 0; i < 4; ++i) a[i] = As[k][ty * 4 + i];
#pragma unroll
      for (int j = 0; j < 4; ++j) b[j] = Bs[k][tx * 4 + j];
#pragma unroll
      for (int i = 0; i < 4; ++i)
#pragma unroll
        for (int j = 0; j < 4; ++j) acc[i][j] += a[i] * b[j];
    }
    __syncthreads();
  }

#pragma unroll
  for (int i = 0; i < 4; ++i) {
    int m = bm + ty * 4 + i;
#pragma unroll
    for (int j = 0; j < 4; ++j) {
      int c = bn + tx * 4 + j;
      float v = acc[i][j] + bias[c];
      if (OUT_MODE == 0) {
        C[(size_t)m * N + c] = v;
      } else {
        int b = m / Nseq, iseq = m % Nseq;
        int h = c >> 6, d = c & 63;
        C[(((size_t)(b * Hh + h)) * Nseq + iseq) * 64 + d] = v;
      }
    }
  }
}

// ---------------------------------------------------------------------------
// attn_scores: per block = (b, h, i-tile of 16). 4 waves, wave w covers
// j in [w*128, w*128+128). MFMA QK^T + Pk, softmax across waves via LDS,
// store normalized P as bf16 [bh][i][j].
// ---------------------------------------------------------------------------
__global__ __launch_bounds__(256) void attn_scores(const float* __restrict__ Qw,
                                                   const float* __restrict__ Kw,
                                                   const float* __restrict__ Pk,
                                                   unsigned short* __restrict__ Pws) {
  const int i0 = blockIdx.x * 16;
  const int h = blockIdx.y, b = blockIdx.z;
  const int bh = b * Hh + h;
  const int tid = threadIdx.x;
  const int w = tid >> 6;
  const int lane = tid & 63;
  const int lo = lane & 15, quad = lane >> 4;

  __shared__ float pk_lds[544];
  __shared__ float redm[4][16];
  __shared__ float redl[4][16];

  // Pk slice: idx t = j - (i-i0) + 15, t in [0,527)
  for (int t = tid; t < 527; t += 256)
    pk_lds[t] = Pk[(size_t)(ZOFF - i0 - 15 + t) * Hh + h];
  __syncthreads();

  // Q A-fragments (row m = lane&15, k = kt*32 + quad*8 + e)
  const float* qbase = Qw + ((size_t)bh * Nseq + i0 + lo) * 64;
  bf16x8 qa0 = ld8_bf16(qbase + quad * 8);
  bf16x8 qa1 = ld8_bf16(qbase + 32 + quad * 8);

  const int jw = w * 128;
  f32x4 acc[8];
#pragma unroll
  for (int s = 0; s < 8; ++s) {
    const float* kbase = Kw + ((size_t)bh * Nseq + jw + s * 16 + lo) * 64;
    bf16x8 kb0 = ld8_bf16(kbase + quad * 8);
    bf16x8 kb1 = ld8_bf16(kbase + 32 + quad * 8);
    f32x4 c = {0.f, 0.f, 0.f, 0.f};
    c = __builtin_amdgcn_mfma_f32_16x16x32_bf16(qa0, kb0, c, 0, 0, 0);
    c = __builtin_amdgcn_mfma_f32_16x16x32_bf16(qa1, kb1, c, 0, 0, 0);
    acc[s] = c;
  }

  // + Pk, * scale; per-row max (row = quad*4 + r)
  float sv[8][4];
  float mrow[4] = {-1e30f, -1e30f, -1e30f, -1e30f};
#pragma unroll
  for (int s = 0; s < 8; ++s) {
    int j = jw + s * 16 + lo;
#pragma unroll
    for (int r = 0; r < 4; ++r) {
      int rl = quad * 4 + r;
      float v = (acc[s][r] + pk_lds[j - rl + 15]) * 0.125f;
      sv[s][r] = v;
      mrow[r] = fmaxf(mrow[r], v);
    }
  }
#pragma unroll
  for (int m = 1; m <= 8; m <<= 1)
#pragma unroll
    for (int r = 0; r < 4; ++r) mrow[r] = fmaxf(mrow[r], __shfl_xor(mrow[r], m));
  if (lo == 0)
#pragma unroll
    for (int r = 0; r < 4; ++r) redm[w][quad * 4 + r] = mrow[r];
  __syncthreads();
  float mfin[4];
#pragma unroll
  for (int r = 0; r < 4; ++r) {
    int rl = quad * 4 + r;
    mfin[r] = fmaxf(fmaxf(redm[0][rl], redm[1][rl]), fmaxf(redm[2][rl], redm[3][rl]));
  }
  // sumexp
  float lrow[4] = {0.f, 0.f, 0.f, 0.f};
#pragma unroll
  for (int s = 0; s < 8; ++s)
#pragma unroll
    for (int r = 0; r < 4; ++r) {
      float e = __expf(sv[s][r] - mfin[r]);
      sv[s][r] = e;
      lrow[r] += e;
    }
#pragma unroll
  for (int m = 1; m <= 8; m <<= 1)
#pragma unroll
    for (int r = 0; r < 4; ++r) lrow[r] += __shfl_xor(lrow[r], m);
  if (lo == 0)
#pragma unroll
    for (int r = 0; r < 4; ++r) redl[w][quad * 4 + r] = lrow[r];
  __syncthreads();
#pragma unroll
  for (int r = 0; r < 4; ++r) {
    int rl = quad * 4 + r;
    float linv = 1.f / (redl[0][rl] + redl[1][rl] + redl[2][rl] + redl[3][rl]);
    int i = i0 + rl;
#pragma unroll
    for (int s = 0; s < 8; ++s) {
      int j = jw + s * 16 + lo;
      Pws[((size_t)(bh * Nseq + i)) * Nseq + j] = f2bf(sv[s][r] * linv);
    }
  }
}

// ---------------------------------------------------------------------------
// attn_pv: per block = (b, h, i-tile of 16). out[i][d] = sum_j P[i,j]*V[j,d]
//          + sum_t P'[i,t]*Pv[zoff+t,h,d]   (P'[i,t]=P[i,i+t], shifted GEMM)
// 4 waves; wave w owns d-tile [w*16, w*16+16). One 16x16 fp32 acc per wave.
// ---------------------------------------------------------------------------
#define PSTR 568  // bf16 elems per LDS P row (16B-aligned stride, 71*16 B)

__device__ __forceinline__ int bt_idx(int d, int kk) {
  return d * 40 + ((d >> 3) << 3) + kk;  // skew breaks dbase bank collisions
}

__global__ __launch_bounds__(256) void attn_pv(const unsigned short* __restrict__ Pws,
                                               const float* __restrict__ Vw,
                                               const float* __restrict__ Pv,
                                               float* __restrict__ Aw) {
  const int i0 = blockIdx.x * 16;
  const int h = blockIdx.y, b = blockIdx.z;
  const int bh = b * Hh + h;
  const int tid = threadIdx.x;
  const int w = tid >> 6;
  const int lane = tid & 63;
  const int lo = lane & 15, quad = lane >> 4;

  __shared__ __align__(16) unsigned short pstrip[16 * PSTR];  // row m, col j
  __shared__ __align__(16) unsigned short pshift[16 * PSTR];  // row m, col j-m+15
  __shared__ __align__(16) unsigned short btile[2624];        // [d][kk] skewed

  // zero strips (pads must be 0)
  int4 z4; z4.x = z4.y = z4.z = z4.w = 0;
  for (int c = tid; c < 1136; c += 256) ((int4*)pstrip)[c] = z4;
  for (int c = tid; c < 1136; c += 256) ((int4*)pshift)[c] = z4;
  __syncthreads();

  // load P strip (16 rows x 512 bf16) into both layouts
  for (int c = tid; c < 1024; c += 256) {
    int r = c >> 6, col = (c & 63) << 3;
    bf16x8 v = *(const bf16x8*)(Pws + ((size_t)(bh * Nseq + i0 + r)) * Nseq + col);
    *(bf16x8*)(pstrip + r * PSTR + col) = v;
    unsigned short* dst = pshift + r * PSTR + 15 - r + col;
#pragma unroll
    for (int u = 0; u < 8; ++u) dst[u] = (unsigned short)v[u];
  }

  f32x4 oacc = {0.f, 0.f, 0.f, 0.f};
  const int d = w * 16 + lo;
  const int kk = tid >> 3, dbase = (tid & 7) << 3;

  // ---- V GEMM: K-extent 512, 16 steps of 32 ----
  for (int ks = 0; ks < 16; ++ks) {
    const int k0 = ks * 32;
    const float* vp = Vw + ((size_t)bh * Nseq + k0 + kk) * 64 + dbase;
    float4 a = *(const float4*)vp;
    float4 bb = *(const float4*)(vp + 4);
    __syncthreads();  // prior reads of btile done (also covers pstrip fill at ks=0)
    float vals[8] = {a.x, a.y, a.z, a.w, bb.x, bb.y, bb.z, bb.w};
#pragma unroll
    for (int u = 0; u < 8; ++u) btile[bt_idx(dbase + u, kk)] = f2bf(vals[u]);
    __syncthreads();
    bf16x8 pa = *(const bf16x8*)(pstrip + lo * PSTR + k0 + quad * 8);
    bf16x8 vb = *(const bf16x8*)(btile + bt_idx(d, quad * 8));
    oacc = __builtin_amdgcn_mfma_f32_16x16x32_bf16(pa, vb, oacc, 0, 0, 0);
  }

  // ---- Pv shifted GEMM: K-extent 544 (valid 527, zero-padded), 17 steps ----
  const int tminrow = ZOFF - i0 - 15;  // Pv row for t-index 0 (>= 0)
  for (int ks = 0; ks < 17; ++ks) {
    const int kb = ks * 32;
    int g = tminrow + kb + kk;
    g = g > 1022 ? 1022 : g;  // clamp; P' is 0 there anyway
    const float* pvp = Pv + ((size_t)g * Hh + h) * 64 + dbase;
    float4 a = *(const float4*)pvp;
    float4 bb = *(const float4*)(pvp + 4);
    __syncthreads();
    float vals[8] = {a.x, a.y, a.z, a.w, bb.x, bb.y, bb.z, bb.w};
#pragma unroll
    for (int u = 0; u < 8; ++u) btile[bt_idx(dbase + u, kk)] = f2bf(vals[u]);
    __syncthreads();
    bf16x8 pa = *(const bf16x8*)(pshift + lo * PSTR + kb + quad * 8);
    bf16x8 vb = *(const bf16x8*)(btile + bt_idx(d, quad * 8));
    oacc = __builtin_amdgcn_mfma_f32_16x16x32_bf16(pa, vb, oacc, 0, 0, 0);
  }

  // write out: row i = i0 + quad*4 + r, col = h*64 + d  (layout [b,i,h*64+d])
#pragma unroll
  for (int r = 0; r < 4; ++r) {
    int i = i0 + quad * 4 + r;
    Aw[((size_t)(b * Nseq + i)) * (Hh * 64) + h * 64 + d] = oacc[r];
  }
}

// ---------------------------------------------------------------------------
extern "C" void kernel_launch(void* const* d_in, const int* in_sizes, int n_in,
                              void* d_out, int out_size, void* d_ws, size_t ws_size,
                              hipStream_t stream) {
  const float* X  = (const float*)d_in[0];
  const float* Wq = (const float*)d_in[1];
  const float* bq = (const float*)d_in[2];
  const float* Wk = (const float*)d_in[3];
  const float* bk = (const float*)d_in[4];
  const float* Wv = (const float*)d_in[5];
  const float* bv = (const float*)d_in[6];
  const float* Wo = (const float*)d_in[7];
  const float* bo = (const float*)d_in[8];
  const float* Pk = (const float*)d_in[9];
  const float* Pv = (const float*)d_in[10];
  float* out = (float*)d_out;

  const int M = Bc * Nseq;                          // 4096
  const size_t per = (size_t)Bc * Hh * Nseq * 64;   // 2,097,152 floats

  // ws layout: [Pws 32MB][Qw 8MB][Kw 8MB][Vw 8MB]; Aw aliases Qw (dead after scores)
  unsigned short* Pws = (unsigned short*)d_ws;
  float* Qw = (float*)((char*)d_ws + (size_t)32 * 1024 * 1024);
  float* Kw = Qw + per;
  float* Vw = Kw + per;
  float* Aw = Qw;

  dim3 gGemm(DM / 64, M / 64);
  dim3 blk(256);

  gemm_bias<1><<<gGemm, blk, 0, stream>>>(X, Wq, bq, Qw, M, Hh * 64, DM);
  gemm_bias<1><<<gGemm, blk, 0, stream>>>(X, Wk, bk, Kw, M, Hh * 64, DM);
  gemm_bias<1><<<gGemm, blk, 0, stream>>>(X, Wv, bv, Vw, M, Hh * 64, DM);

  dim3 gAttn(Nseq / 16, Hh, Bc);  // (32, 8, 8)
  attn_scores<<<gAttn, blk, 0, stream>>>(Qw, Kw, Pk, Pws);
  attn_pv<<<gAttn, blk, 0, stream>>>(Pws, Vw, Pv, Aw);

  gemm_bias<0><<<gGemm, blk, 0, stream>>>(Aw, Wo, bo, out, M, DM, Hh * 64);
}

// Round 3
// 220.235 us; speedup vs baseline: 7.0694x; 2.0410x over previous
//
#include <hip/hip_runtime.h>
#include <math.h>

#define Bc 8
#define Nseq 512
#define DM 512
#define Hh 8
#define NUMREL 1023
#define ZOFF 511   // NUMREL/2

typedef short bf16x8 __attribute__((ext_vector_type(8)));
typedef float f32x4 __attribute__((ext_vector_type(4)));

__device__ __forceinline__ unsigned short f2bf(float f) {
  unsigned u = __builtin_bit_cast(unsigned, f);
  u += 0x7fff + ((u >> 16) & 1);   // RNE
  return (unsigned short)(u >> 16);
}
__device__ __forceinline__ float bf2f(unsigned short h) {
  unsigned u = ((unsigned)h) << 16;
  return __builtin_bit_cast(float, u);
}

// ---------------------------------------------------------------------------
// prep_cvt: X (fp32->bf16, 2M elems) and Pv (fp32->bf16, 523776 elems), x4 vec
// ---------------------------------------------------------------------------
__global__ __launch_bounds__(256) void prep_cvt(const float* __restrict__ X,
                                                const float* __restrict__ Pv,
                                                unsigned short* __restrict__ Xb,
                                                unsigned short* __restrict__ Pvb) {
  const int n1 = Bc * Nseq * DM / 4;      // 524288
  const int n2 = NUMREL * Hh * 64 / 4;    // 130944
  int idx = blockIdx.x * 256 + threadIdx.x;
  if (idx < n1) {
    float4 v = ((const float4*)X)[idx];
    ushort4 o;
    o.x = f2bf(v.x); o.y = f2bf(v.y); o.z = f2bf(v.z); o.w = f2bf(v.w);
    ((ushort4*)Xb)[idx] = o;
  } else if (idx < n1 + n2) {
    int j = idx - n1;
    float4 v = ((const float4*)Pv)[j];
    ushort4 o;
    o.x = f2bf(v.x); o.y = f2bf(v.y); o.z = f2bf(v.z); o.w = f2bf(v.w);
    ((ushort4*)Pvb)[j] = o;
  }
}

// ---------------------------------------------------------------------------
// wtrans: W[K,N] -> Wt[n][k] bf16. z=0..2: Wq/Wk/Wv; z=3: Wo hi; z=4: Wo lo.
// ---------------------------------------------------------------------------
__global__ __launch_bounds__(256) void wtrans(const float* __restrict__ Wq,
                                              const float* __restrict__ Wk,
                                              const float* __restrict__ Wv,
                                              const float* __restrict__ Wo,
                                              unsigned short* __restrict__ Wqt,
                                              unsigned short* __restrict__ Wkt,
                                              unsigned short* __restrict__ Wvt,
                                              unsigned short* __restrict__ Woth,
                                              unsigned short* __restrict__ Wotl) {
  const int z = blockIdx.z;
  const float* src = z == 0 ? Wq : z == 1 ? Wk : z == 2 ? Wv : Wo;
  unsigned short* dst = z == 0 ? Wqt : z == 1 ? Wkt : z == 2 ? Wvt : z == 3 ? Woth : Wotl;
  const int k0 = blockIdx.y * 32, n0 = blockIdx.x * 32;
  __shared__ float t[32][33];
  const int tid = threadIdx.x;
#pragma unroll
  for (int u = 0; u < 4; ++u) {
    int idx = u * 256 + tid, r = idx >> 5, c = idx & 31;
    t[r][c] = src[(size_t)(k0 + r) * DM + n0 + c];
  }
  __syncthreads();
#pragma unroll
  for (int u = 0; u < 4; ++u) {
    int idx = u * 256 + tid, r = idx >> 5, c = idx & 31;
    float v = t[c][r];
    unsigned short hv = f2bf(v);
    if (z == 4) hv = f2bf(v - bf2f(hv));
    dst[(size_t)(n0 + r) * DM + k0 + c] = hv;
  }
}

// ---------------------------------------------------------------------------
// gemm_qkv: bf16 MFMA, no LDS. A=Xb [4096][512] bf16, B=Wt [n][k] bf16.
// Out bf16 in QKV layout [(b*H+h)*N + i][64]. grid (8, 64, 3), block 256.
// ---------------------------------------------------------------------------
__global__ __launch_bounds__(256) void gemm_qkv(const unsigned short* __restrict__ Xb,
                                                const unsigned short* __restrict__ Wqt,
                                                const unsigned short* __restrict__ Wkt,
                                                const unsigned short* __restrict__ Wvt,
                                                const float* __restrict__ bq,
                                                const float* __restrict__ bk,
                                                const float* __restrict__ bv,
                                                unsigned short* __restrict__ Qb,
                                                unsigned short* __restrict__ Kb,
                                                unsigned short* __restrict__ Vb) {
  const int z = blockIdx.z;
  const unsigned short* Wt = z == 0 ? Wqt : z == 1 ? Wkt : Wvt;
  const float* bias = z == 0 ? bq : z == 1 ? bk : bv;
  unsigned short* Out = z == 0 ? Qb : z == 1 ? Kb : Vb;

  const int bm = blockIdx.y * 64, bn = blockIdx.x * 64;
  const int tid = threadIdx.x, w = tid >> 6, lane = tid & 63;
  const int lo = lane & 15, quad = lane >> 4;
  const int mt = (w >> 1) * 32, nt = (w & 1) * 32;

  f32x4 acc[2][2] = {};
#pragma unroll 2
  for (int k0 = 0; k0 < DM; k0 += 32) {
    bf16x8 af[2], bf[2];
#pragma unroll
    for (int i = 0; i < 2; ++i)
      af[i] = *(const bf16x8*)(Xb + (size_t)(bm + mt + i * 16 + lo) * DM + k0 + quad * 8);
#pragma unroll
    for (int j = 0; j < 2; ++j)
      bf[j] = *(const bf16x8*)(Wt + (size_t)(bn + nt + j * 16 + lo) * DM + k0 + quad * 8);
#pragma unroll
    for (int i = 0; i < 2; ++i)
#pragma unroll
      for (int j = 0; j < 2; ++j)
        acc[i][j] = __builtin_amdgcn_mfma_f32_16x16x32_bf16(af[i], bf[j], acc[i][j], 0, 0, 0);
  }

#pragma unroll
  for (int i = 0; i < 2; ++i)
#pragma unroll
    for (int j = 0; j < 2; ++j) {
      int col = bn + nt + j * 16 + lo;
      int h = col >> 6, d = col & 63;
      float bv_ = bias[col];
#pragma unroll
      for (int r = 0; r < 4; ++r) {
        int row = bm + mt + i * 16 + quad * 4 + r;
        int b = row >> 9, is = row & 511;
        Out[((size_t)(b * Hh + h) * Nseq + is) * 64 + d] = f2bf(acc[i][j][r] + bv_);
      }
    }
}

// ---------------------------------------------------------------------------
// attn_fused: per block = (b, h, 16-row i-tile). Phase 1: QK^T + Pk softmax
// -> normalized P bf16 into LDS (unshifted + shifted). Phase 2: P@V + P'@Pv
// MFMA. Out: Aw hi/lo bf16 [b*N+i][512].
// ---------------------------------------------------------------------------
#define PSTR 568  // bf16 elems per LDS P row

__device__ __forceinline__ int bt_idx(int d, int kk) {
  return d * 40 + ((d >> 3) << 3) + kk;
}

__global__ __launch_bounds__(256) void attn_fused(const unsigned short* __restrict__ Qb,
                                                  const unsigned short* __restrict__ Kb,
                                                  const unsigned short* __restrict__ Vb,
                                                  const float* __restrict__ Pk,
                                                  const unsigned short* __restrict__ Pvb,
                                                  unsigned short* __restrict__ Awh,
                                                  unsigned short* __restrict__ Awl) {
  const int i0 = blockIdx.x * 16;
  const int h = blockIdx.y, b = blockIdx.z;
  const int bh = b * Hh + h;
  const int tid = threadIdx.x;
  const int w = tid >> 6;
  const int lane = tid & 63;
  const int lo = lane & 15, quad = lane >> 4;

  __shared__ __align__(16) unsigned short pstrip[16 * PSTR];
  __shared__ __align__(16) unsigned short pshift[16 * PSTR];
  __shared__ __align__(16) unsigned short btile[2624];
  __shared__ float pk_lds[544];
  __shared__ float redm[4][16];
  __shared__ float redl[4][16];

  // zero P strips (pads must be 0)
  int4 z4; z4.x = z4.y = z4.z = z4.w = 0;
  for (int c = tid; c < 1136; c += 256) ((int4*)pstrip)[c] = z4;
  for (int c = tid; c < 1136; c += 256) ((int4*)pshift)[c] = z4;
  for (int t = tid; t < 527; t += 256)
    pk_lds[t] = Pk[(size_t)(ZOFF - i0 - 15 + t) * Hh + h];
  __syncthreads();

  // ---------------- Phase 1: scores + softmax ----------------
  const unsigned short* qbase = Qb + ((size_t)bh * Nseq + i0 + lo) * 64;
  bf16x8 qa0 = *(const bf16x8*)(qbase + quad * 8);
  bf16x8 qa1 = *(const bf16x8*)(qbase + 32 + quad * 8);

  const int jw = w * 128;
  float sv[8][4];
  float mrow[4] = {-1e30f, -1e30f, -1e30f, -1e30f};
#pragma unroll
  for (int s = 0; s < 8; ++s) {
    const unsigned short* kbase = Kb + ((size_t)bh * Nseq + jw + s * 16 + lo) * 64;
    bf16x8 kb0 = *(const bf16x8*)(kbase + quad * 8);
    bf16x8 kb1 = *(const bf16x8*)(kbase + 32 + quad * 8);
    f32x4 c = {0.f, 0.f, 0.f, 0.f};
    c = __builtin_amdgcn_mfma_f32_16x16x32_bf16(qa0, kb0, c, 0, 0, 0);
    c = __builtin_amdgcn_mfma_f32_16x16x32_bf16(qa1, kb1, c, 0, 0, 0);
    int j = jw + s * 16 + lo;
#pragma unroll
    for (int r = 0; r < 4; ++r) {
      int rl = quad * 4 + r;
      float v = (c[r] + pk_lds[j - rl + 15]) * 0.125f;
      sv[s][r] = v;
      mrow[r] = fmaxf(mrow[r], v);
    }
  }
#pragma unroll
  for (int m = 1; m <= 8; m <<= 1)
#pragma unroll
    for (int r = 0; r < 4; ++r) mrow[r] = fmaxf(mrow[r], __shfl_xor(mrow[r], m));
  if (lo == 0)
#pragma unroll
    for (int r = 0; r < 4; ++r) redm[w][quad * 4 + r] = mrow[r];
  __syncthreads();
  float mfin[4];
#pragma unroll
  for (int r = 0; r < 4; ++r) {
    int rl = quad * 4 + r;
    mfin[r] = fmaxf(fmaxf(redm[0][rl], redm[1][rl]), fmaxf(redm[2][rl], redm[3][rl]));
  }
  float lrow[4] = {0.f, 0.f, 0.f, 0.f};
#pragma unroll
  for (int s = 0; s < 8; ++s)
#pragma unroll
    for (int r = 0; r < 4; ++r) {
      float e = __expf(sv[s][r] - mfin[r]);
      sv[s][r] = e;
      lrow[r] += e;
    }
#pragma unroll
  for (int m = 1; m <= 8; m <<= 1)
#pragma unroll
    for (int r = 0; r < 4; ++r) lrow[r] += __shfl_xor(lrow[r], m);
  if (lo == 0)
#pragma unroll
    for (int r = 0; r < 4; ++r) redl[w][quad * 4 + r] = lrow[r];
  __syncthreads();
#pragma unroll
  for (int r = 0; r < 4; ++r) {
    int rl = quad * 4 + r;
    float linv = 1.f / (redl[0][rl] + redl[1][rl] + redl[2][rl] + redl[3][rl]);
#pragma unroll
    for (int s = 0; s < 8; ++s) {
      int j = jw + s * 16 + lo;
      unsigned short pb = f2bf(sv[s][r] * linv);
      pstrip[rl * PSTR + j] = pb;
      pshift[rl * PSTR + j - rl + 15] = pb;
    }
  }
  __syncthreads();

  // ---------------- Phase 2: P@V + P'@Pv ----------------
  f32x4 oacc = {0.f, 0.f, 0.f, 0.f};
  const int d = w * 16 + lo;
  const int kk = tid >> 3, dbase = (tid & 7) << 3;

  // V GEMM: K-extent 512
  for (int ks = 0; ks < 16; ++ks) {
    const int k0 = ks * 32;
    bf16x8 vv = *(const bf16x8*)(Vb + ((size_t)bh * Nseq + k0 + kk) * 64 + dbase);
    __syncthreads();
#pragma unroll
    for (int u = 0; u < 8; ++u) btile[bt_idx(dbase + u, kk)] = (unsigned short)vv[u];
    __syncthreads();
    bf16x8 pa = *(const bf16x8*)(pstrip + lo * PSTR + k0 + quad * 8);
    bf16x8 vb = *(const bf16x8*)(btile + bt_idx(d, quad * 8));
    oacc = __builtin_amdgcn_mfma_f32_16x16x32_bf16(pa, vb, oacc, 0, 0, 0);
  }

  // Pv shifted GEMM: K-extent 544 (valid 527, zero-padded)
  const int tminrow = ZOFF - i0 - 15;
  for (int ks = 0; ks < 17; ++ks) {
    const int kb = ks * 32;
    int g = tminrow + kb + kk;
    g = g > 1022 ? 1022 : g;
    bf16x8 pv = *(const bf16x8*)(Pvb + ((size_t)g * Hh + h) * 64 + dbase);
    __syncthreads();
#pragma unroll
    for (int u = 0; u < 8; ++u) btile[bt_idx(dbase + u, kk)] = (unsigned short)pv[u];
    __syncthreads();
    bf16x8 pa = *(const bf16x8*)(pshift + lo * PSTR + kb + quad * 8);
    bf16x8 vb = *(const bf16x8*)(btile + bt_idx(d, quad * 8));
    oacc = __builtin_amdgcn_mfma_f32_16x16x32_bf16(pa, vb, oacc, 0, 0, 0);
  }

  // write Aw hi/lo bf16, layout [b*N+i][H*64]
#pragma unroll
  for (int r = 0; r < 4; ++r) {
    int i = i0 + quad * 4 + r;
    float o = oacc[r];
    unsigned short hi = f2bf(o);
    unsigned short lov = f2bf(o - bf2f(hi));
    size_t off = ((size_t)(b * Nseq + i)) * (Hh * 64) + h * 64 + d;
    Awh[off] = hi;
    Awl[off] = lov;
  }
}

// ---------------------------------------------------------------------------
// gemm_final: split-bf16 (3-term) MFMA GEMM. out = Ah@Bh + Ah@Bl + Al@Bh + bo
// A [4096][512] bf16 hi/lo, B [n][k] bf16 hi/lo. out fp32 [4096][512].
// ---------------------------------------------------------------------------
__global__ __launch_bounds__(256) void gemm_final(const unsigned short* __restrict__ Ah,
                                                  const unsigned short* __restrict__ Al,
                                                  const unsigned short* __restrict__ Bh,
                                                  const unsigned short* __restrict__ Bl,
                                                  const float* __restrict__ bo,
                                                  float* __restrict__ out) {
  const int bm = blockIdx.y * 64, bn = blockIdx.x * 64;
  const int tid = threadIdx.x, w = tid >> 6, lane = tid & 63;
  const int lo = lane & 15, quad = lane >> 4;
  const int mt = (w >> 1) * 32, nt = (w & 1) * 32;

  f32x4 acc[2][2] = {};
  for (int k0 = 0; k0 < DM; k0 += 32) {
    bf16x8 ah[2], al[2], bh[2], bl[2];
#pragma unroll
    for (int i = 0; i < 2; ++i) {
      size_t off = (size_t)(bm + mt + i * 16 + lo) * DM + k0 + quad * 8;
      ah[i] = *(const bf16x8*)(Ah + off);
      al[i] = *(const bf16x8*)(Al + off);
    }
#pragma unroll
    for (int j = 0; j < 2; ++j) {
      size_t off = (size_t)(bn + nt + j * 16 + lo) * DM + k0 + quad * 8;
      bh[j] = *(const bf16x8*)(Bh + off);
      bl[j] = *(const bf16x8*)(Bl + off);
    }
#pragma unroll
    for (int i = 0; i < 2; ++i)
#pragma unroll
      for (int j = 0; j < 2; ++j) {
        acc[i][j] = __builtin_amdgcn_mfma_f32_16x16x32_bf16(ah[i], bh[j], acc[i][j], 0, 0, 0);
        acc[i][j] = __builtin_amdgcn_mfma_f32_16x16x32_bf16(ah[i], bl[j], acc[i][j], 0, 0, 0);
        acc[i][j] = __builtin_amdgcn_mfma_f32_16x16x32_bf16(al[i], bh[j], acc[i][j], 0, 0, 0);
      }
  }

#pragma unroll
  for (int i = 0; i < 2; ++i)
#pragma unroll
    for (int j = 0; j < 2; ++j) {
      int col = bn + nt + j * 16 + lo;
      float bb = bo[col];
#pragma unroll
      for (int r = 0; r < 4; ++r) {
        int row = bm + mt + i * 16 + quad * 4 + r;
        out[(size_t)row * DM + col] = acc[i][j][r] + bb;
      }
    }
}

// ---------------------------------------------------------------------------
extern "C" void kernel_launch(void* const* d_in, const int* in_sizes, int n_in,
                              void* d_out, int out_size, void* d_ws, size_t ws_size,
                              hipStream_t stream) {
  const float* X  = (const float*)d_in[0];
  const float* Wq = (const float*)d_in[1];
  const float* bq = (const float*)d_in[2];
  const float* Wk = (const float*)d_in[3];
  const float* bk = (const float*)d_in[4];
  const float* Wv = (const float*)d_in[5];
  const float* bv = (const float*)d_in[6];
  const float* Wo = (const float*)d_in[7];
  const float* bo = (const float*)d_in[8];
  const float* Pk = (const float*)d_in[9];
  const float* Pv = (const float*)d_in[10];
  float* out = (float*)d_out;

  // workspace layout (bf16 elements)
  char* p = (char*)d_ws;
  const size_t szX   = (size_t)Bc * Nseq * DM * 2;          // 4 MB
  const size_t szW   = (size_t)DM * DM * 2;                 // 512 KB
  const size_t szPv  = (size_t)NUMREL * Hh * 64 * 2;        // ~1 MB
  const size_t szQKV = (size_t)Bc * Hh * Nseq * 64 * 2;     // 4 MB
  unsigned short* Xb   = (unsigned short*)p; p += szX;
  unsigned short* Wqt  = (unsigned short*)p; p += szW;
  unsigned short* Wkt  = (unsigned short*)p; p += szW;
  unsigned short* Wvt  = (unsigned short*)p; p += szW;
  unsigned short* Woth = (unsigned short*)p; p += szW;
  unsigned short* Wotl = (unsigned short*)p; p += szW;
  unsigned short* Pvb  = (unsigned short*)p; p += szPv;
  unsigned short* Qb   = (unsigned short*)p; p += szQKV;
  unsigned short* Kb   = (unsigned short*)p; p += szQKV;
  unsigned short* Vb   = (unsigned short*)p; p += szQKV;
  unsigned short* Awh  = (unsigned short*)p; p += szX;
  unsigned short* Awl  = (unsigned short*)p; p += szX;

  dim3 blk(256);
  prep_cvt<<<dim3(2560), blk, 0, stream>>>(X, Pv, Xb, Pvb);
  wtrans<<<dim3(16, 16, 5), blk, 0, stream>>>(Wq, Wk, Wv, Wo, Wqt, Wkt, Wvt, Woth, Wotl);
  gemm_qkv<<<dim3(8, 64, 3), blk, 0, stream>>>(Xb, Wqt, Wkt, Wvt, bq, bk, bv, Qb, Kb, Vb);
  attn_fused<<<dim3(Nseq / 16, Hh, Bc), blk, 0, stream>>>(Qb, Kb, Vb, Pk, Pvb, Awh, Awl);
  gemm_final<<<dim3(8, 64), blk, 0, stream>>>(Awh, Awl, Woth, Wotl, bo, out);
}

// Round 4
// 209.675 us; speedup vs baseline: 7.4254x; 1.0504x over previous
//
#include <hip/hip_runtime.h>
#include <math.h>

#define Bc 8
#define Nseq 512
#define DM 512
#define Hh 8
#define NUMREL 1023
#define ZOFF 511   // NUMREL/2
#define PVROWS 1040  // Pvt padded g-extent (>= 496+544, mult of 16)

typedef short bf16x8 __attribute__((ext_vector_type(8)));
typedef float f32x4 __attribute__((ext_vector_type(4)));

__device__ __forceinline__ unsigned short f2bf(float f) {
  unsigned u = __builtin_bit_cast(unsigned, f);
  u += 0x7fff + ((u >> 16) & 1);   // RNE
  return (unsigned short)(u >> 16);
}
__device__ __forceinline__ float bf2f(unsigned short h) {
  unsigned u = ((unsigned)h) << 16;
  return __builtin_bit_cast(float, u);
}

// ---------------------------------------------------------------------------
// prep_cvt: X fp32 -> bf16 (2M elems), float4 vectorized.
// ---------------------------------------------------------------------------
__global__ __launch_bounds__(256) void prep_cvt(const float* __restrict__ X,
                                                unsigned short* __restrict__ Xb) {
  int idx = blockIdx.x * 256 + threadIdx.x;
  float4 v = ((const float4*)X)[idx];
  ushort4 o;
  o.x = f2bf(v.x); o.y = f2bf(v.y); o.z = f2bf(v.z); o.w = f2bf(v.w);
  ((ushort4*)Xb)[idx] = o;
}

// ---------------------------------------------------------------------------
// pv_trans: Pv [1023][8][64] fp32 -> Pvt [8*64][PVROWS] bf16 (g-contiguous,
// zero-padded rows g in [1023, PVROWS)). grid (17, 8).
// ---------------------------------------------------------------------------
__global__ __launch_bounds__(256) void pv_trans(const float* __restrict__ Pv,
                                                unsigned short* __restrict__ Pvt) {
  const int g0 = blockIdx.x * 64, hd0 = blockIdx.y * 64;
  __shared__ float t[64][65];
  const int tid = threadIdx.x;
#pragma unroll
  for (int u = 0; u < 16; ++u) {
    int idx = u * 256 + tid, r = idx >> 6, c = idx & 63;
    int g = g0 + r;
    t[r][c] = g < NUMREL ? Pv[(size_t)g * 512 + hd0 + c] : 0.f;
  }
  __syncthreads();
#pragma unroll
  for (int u = 0; u < 16; ++u) {
    int idx = u * 256 + tid, r = idx >> 6, c = idx & 63;
    int g = g0 + c;
    if (g < PVROWS) Pvt[(size_t)(hd0 + r) * PVROWS + g] = f2bf(t[c][r]);
  }
}

// ---------------------------------------------------------------------------
// wtrans: W[K,N] -> Wt[n][k] bf16. z=0..2: Wq/Wk/Wv; z=3: Wo hi; z=4: Wo lo.
// ---------------------------------------------------------------------------
__global__ __launch_bounds__(256) void wtrans(const float* __restrict__ Wq,
                                              const float* __restrict__ Wk,
                                              const float* __restrict__ Wv,
                                              const float* __restrict__ Wo,
                                              unsigned short* __restrict__ Wqt,
                                              unsigned short* __restrict__ Wkt,
                                              unsigned short* __restrict__ Wvt,
                                              unsigned short* __restrict__ Woth,
                                              unsigned short* __restrict__ Wotl) {
  const int z = blockIdx.z;
  const float* src = z == 0 ? Wq : z == 1 ? Wk : z == 2 ? Wv : Wo;
  unsigned short* dst = z == 0 ? Wqt : z == 1 ? Wkt : z == 2 ? Wvt : z == 3 ? Woth : Wotl;
  const int k0 = blockIdx.y * 32, n0 = blockIdx.x * 32;
  __shared__ float t[32][33];
  const int tid = threadIdx.x;
#pragma unroll
  for (int u = 0; u < 4; ++u) {
    int idx = u * 256 + tid, r = idx >> 5, c = idx & 31;
    t[r][c] = src[(size_t)(k0 + r) * DM + n0 + c];
  }
  __syncthreads();
#pragma unroll
  for (int u = 0; u < 4; ++u) {
    int idx = u * 256 + tid, r = idx >> 5, c = idx & 31;
    float v = t[c][r];
    unsigned short hv = f2bf(v);
    if (z == 4) hv = f2bf(v - bf2f(hv));
    dst[(size_t)(n0 + r) * DM + k0 + c] = hv;
  }
}

// ---------------------------------------------------------------------------
// gemm_qkv: bf16 MFMA, no LDS. A=Xb [4096][512], B=Wt [n][k].
// z=0: Qb [(bh)*N+i][64]; z=1: Kb same; z=2: Vt [(bh)*64+d][512] (transposed).
// ---------------------------------------------------------------------------
__global__ __launch_bounds__(256) void gemm_qkv(const unsigned short* __restrict__ Xb,
                                                const unsigned short* __restrict__ Wqt,
                                                const unsigned short* __restrict__ Wkt,
                                                const unsigned short* __restrict__ Wvt,
                                                const float* __restrict__ bq,
                                                const float* __restrict__ bk,
                                                const float* __restrict__ bv,
                                                unsigned short* __restrict__ Qb,
                                                unsigned short* __restrict__ Kb,
                                                unsigned short* __restrict__ Vt) {
  const int z = blockIdx.z;
  const unsigned short* Wt = z == 0 ? Wqt : z == 1 ? Wkt : Wvt;
  const float* bias = z == 0 ? bq : z == 1 ? bk : bv;

  const int bm = blockIdx.y * 64, bn = blockIdx.x * 64;
  const int tid = threadIdx.x, w = tid >> 6, lane = tid & 63;
  const int lo = lane & 15, quad = lane >> 4;
  const int mt = (w >> 1) * 32, nt = (w & 1) * 32;

  f32x4 acc[2][2] = {};
#pragma unroll 2
  for (int k0 = 0; k0 < DM; k0 += 32) {
    bf16x8 af[2], bf[2];
#pragma unroll
    for (int i = 0; i < 2; ++i)
      af[i] = *(const bf16x8*)(Xb + (size_t)(bm + mt + i * 16 + lo) * DM + k0 + quad * 8);
#pragma unroll
    for (int j = 0; j < 2; ++j)
      bf[j] = *(const bf16x8*)(Wt + (size_t)(bn + nt + j * 16 + lo) * DM + k0 + quad * 8);
#pragma unroll
    for (int i = 0; i < 2; ++i)
#pragma unroll
      for (int j = 0; j < 2; ++j)
        acc[i][j] = __builtin_amdgcn_mfma_f32_16x16x32_bf16(af[i], bf[j], acc[i][j], 0, 0, 0);
  }

#pragma unroll
  for (int i = 0; i < 2; ++i)
#pragma unroll
    for (int j = 0; j < 2; ++j) {
      int col = bn + nt + j * 16 + lo;
      int h = col >> 6, d = col & 63;
      float bv_ = bias[col];
#pragma unroll
      for (int r = 0; r < 4; ++r) {
        int row = bm + mt + i * 16 + quad * 4 + r;
        int b = row >> 9, is = row & 511;
        unsigned short val = f2bf(acc[i][j][r] + bv_);
        if (z == 2)
          Vt[((size_t)(b * Hh + h) * 64 + d) * 512 + is] = val;
        else if (z == 0)
          Qb[((size_t)(b * Hh + h) * Nseq + is) * 64 + d] = val;
        else
          Kb[((size_t)(b * Hh + h) * Nseq + is) * 64 + d] = val;
      }
    }
}

// ---------------------------------------------------------------------------
// attn_fused: per block = (b, h, 16-row i-tile). Phase 1: QK^T + Pk softmax
// -> P bf16 in LDS (unshifted + shifted). Phase 2: P@V + P'@Pv with B-operands
// loaded DIRECTLY from global (Vt / Pvt, k-contiguous) — no in-loop barriers.
// ---------------------------------------------------------------------------
#define PSV 520  // pstrip row stride (elems): 1040 B = 260 banks, 4*odd -> 2-way
#define PSH 552  // pshift row stride (elems): 1104 B = 276 banks, 4*odd -> 2-way

__global__ __launch_bounds__(256) void attn_fused(const unsigned short* __restrict__ Qb,
                                                  const unsigned short* __restrict__ Kb,
                                                  const unsigned short* __restrict__ Vt,
                                                  const float* __restrict__ Pk,
                                                  const unsigned short* __restrict__ Pvt,
                                                  unsigned short* __restrict__ Awh,
                                                  unsigned short* __restrict__ Awl) {
  const int i0 = blockIdx.x * 16;
  const int h = blockIdx.y, b = blockIdx.z;
  const int bh = b * Hh + h;
  const int tid = threadIdx.x;
  const int w = tid >> 6;
  const int lane = tid & 63;
  const int lo = lane & 15, quad = lane >> 4;

  __shared__ __align__(16) unsigned short pstrip[16 * PSV];
  __shared__ __align__(16) unsigned short pshift[16 * PSH];
  __shared__ float pk_lds[544];
  __shared__ float redm[4][16];
  __shared__ float redl[4][16];

  // zero pshift (pads beyond the diagonal band must be 0); pstrip fully written
  int4 z4; z4.x = z4.y = z4.z = z4.w = 0;
  for (int c = tid; c < 16 * PSH / 8; c += 256) ((int4*)pshift)[c] = z4;
  for (int t = tid; t < 527; t += 256)
    pk_lds[t] = Pk[(size_t)(ZOFF - i0 - 15 + t) * Hh + h];
  __syncthreads();

  // ---------------- Phase 1: scores + softmax ----------------
  const unsigned short* qbase = Qb + ((size_t)bh * Nseq + i0 + lo) * 64;
  bf16x8 qa0 = *(const bf16x8*)(qbase + quad * 8);
  bf16x8 qa1 = *(const bf16x8*)(qbase + 32 + quad * 8);

  const int jw = w * 128;
  float sv[8][4];
  float mrow[4] = {-1e30f, -1e30f, -1e30f, -1e30f};
#pragma unroll
  for (int s = 0; s < 8; ++s) {
    const unsigned short* kbase = Kb + ((size_t)bh * Nseq + jw + s * 16 + lo) * 64;
    bf16x8 kb0 = *(const bf16x8*)(kbase + quad * 8);
    bf16x8 kb1 = *(const bf16x8*)(kbase + 32 + quad * 8);
    f32x4 c = {0.f, 0.f, 0.f, 0.f};
    c = __builtin_amdgcn_mfma_f32_16x16x32_bf16(qa0, kb0, c, 0, 0, 0);
    c = __builtin_amdgcn_mfma_f32_16x16x32_bf16(qa1, kb1, c, 0, 0, 0);
    int j = jw + s * 16 + lo;
#pragma unroll
    for (int r = 0; r < 4; ++r) {
      int rl = quad * 4 + r;
      float v = (c[r] + pk_lds[j - rl + 15]) * 0.125f;
      sv[s][r] = v;
      mrow[r] = fmaxf(mrow[r], v);
    }
  }
#pragma unroll
  for (int m = 1; m <= 8; m <<= 1)
#pragma unroll
    for (int r = 0; r < 4; ++r) mrow[r] = fmaxf(mrow[r], __shfl_xor(mrow[r], m));
  if (lo == 0)
#pragma unroll
    for (int r = 0; r < 4; ++r) redm[w][quad * 4 + r] = mrow[r];
  __syncthreads();
  float mfin[4];
#pragma unroll
  for (int r = 0; r < 4; ++r) {
    int rl = quad * 4 + r;
    mfin[r] = fmaxf(fmaxf(redm[0][rl], redm[1][rl]), fmaxf(redm[2][rl], redm[3][rl]));
  }
  float lrow[4] = {0.f, 0.f, 0.f, 0.f};
#pragma unroll
  for (int s = 0; s < 8; ++s)
#pragma unroll
    for (int r = 0; r < 4; ++r) {
      float e = __expf(sv[s][r] - mfin[r]);
      sv[s][r] = e;
      lrow[r] += e;
    }
#pragma unroll
  for (int m = 1; m <= 8; m <<= 1)
#pragma unroll
    for (int r = 0; r < 4; ++r) lrow[r] += __shfl_xor(lrow[r], m);
  if (lo == 0)
#pragma unroll
    for (int r = 0; r < 4; ++r) redl[w][quad * 4 + r] = lrow[r];
  __syncthreads();
#pragma unroll
  for (int r = 0; r < 4; ++r) {
    int rl = quad * 4 + r;
    float linv = 1.f / (redl[0][rl] + redl[1][rl] + redl[2][rl] + redl[3][rl]);
#pragma unroll
    for (int s = 0; s < 8; ++s) {
      int j = jw + s * 16 + lo;
      unsigned short pb = f2bf(sv[s][r] * linv);
      pstrip[rl * PSV + j] = pb;
      pshift[rl * PSH + j - rl + 15] = pb;
    }
  }
  __syncthreads();

  // ---------------- Phase 2: P@V + P'@Pv (no barriers) ----------------
  f32x4 oacc = {0.f, 0.f, 0.f, 0.f};
  const int d = w * 16 + lo;

  const unsigned short* vrow = Vt + ((size_t)bh * 64 + d) * 512;
#pragma unroll 4
  for (int ks = 0; ks < 16; ++ks) {
    bf16x8 pa = *(const bf16x8*)(pstrip + lo * PSV + ks * 32 + quad * 8);
    bf16x8 vb = *(const bf16x8*)(vrow + ks * 32 + quad * 8);
    oacc = __builtin_amdgcn_mfma_f32_16x16x32_bf16(pa, vb, oacc, 0, 0, 0);
  }

  const int tminrow = ZOFF - i0 - 15;  // multiple of 16, >= 0
  const unsigned short* pvrow = Pvt + ((size_t)h * 64 + d) * PVROWS + tminrow;
#pragma unroll 4
  for (int ks = 0; ks < 17; ++ks) {
    bf16x8 pa = *(const bf16x8*)(pshift + lo * PSH + ks * 32 + quad * 8);
    bf16x8 vb = *(const bf16x8*)(pvrow + ks * 32 + quad * 8);
    oacc = __builtin_amdgcn_mfma_f32_16x16x32_bf16(pa, vb, oacc, 0, 0, 0);
  }

  // write Aw hi/lo bf16, layout [b*N+i][H*64]
#pragma unroll
  for (int r = 0; r < 4; ++r) {
    int i = i0 + quad * 4 + r;
    float o = oacc[r];
    unsigned short hi = f2bf(o);
    unsigned short lov = f2bf(o - bf2f(hi));
    size_t off = ((size_t)(b * Nseq + i)) * (Hh * 64) + h * 64 + d;
    Awh[off] = hi;
    Awl[off] = lov;
  }
}

// ---------------------------------------------------------------------------
// gemm_final: split-bf16 (3-term) MFMA GEMM. out = Ah@Bh + Ah@Bl + Al@Bh + bo
// ---------------------------------------------------------------------------
__global__ __launch_bounds__(256) void gemm_final(const unsigned short* __restrict__ Ah,
                                                  const unsigned short* __restrict__ Al,
                                                  const unsigned short* __restrict__ Bh,
                                                  const unsigned short* __restrict__ Bl,
                                                  const float* __restrict__ bo,
                                                  float* __restrict__ out) {
  const int bm = blockIdx.y * 64, bn = blockIdx.x * 64;
  const int tid = threadIdx.x, w = tid >> 6, lane = tid & 63;
  const int lo = lane & 15, quad = lane >> 4;
  const int mt = (w >> 1) * 32, nt = (w & 1) * 32;

  f32x4 acc[2][2] = {};
  for (int k0 = 0; k0 < DM; k0 += 32) {
    bf16x8 ah[2], al[2], bh[2], bl[2];
#pragma unroll
    for (int i = 0; i < 2; ++i) {
      size_t off = (size_t)(bm + mt + i * 16 + lo) * DM + k0 + quad * 8;
      ah[i] = *(const bf16x8*)(Ah + off);
      al[i] = *(const bf16x8*)(Al + off);
    }
#pragma unroll
    for (int j = 0; j < 2; ++j) {
      size_t off = (size_t)(bn + nt + j * 16 + lo) * DM + k0 + quad * 8;
      bh[j] = *(const bf16x8*)(Bh + off);
      bl[j] = *(const bf16x8*)(Bl + off);
    }
#pragma unroll
    for (int i = 0; i < 2; ++i)
#pragma unroll
      for (int j = 0; j < 2; ++j) {
        acc[i][j] = __builtin_amdgcn_mfma_f32_16x16x32_bf16(ah[i], bh[j], acc[i][j], 0, 0, 0);
        acc[i][j] = __builtin_amdgcn_mfma_f32_16x16x32_bf16(ah[i], bl[j], acc[i][j], 0, 0, 0);
        acc[i][j] = __builtin_amdgcn_mfma_f32_16x16x32_bf16(al[i], bh[j], acc[i][j], 0, 0, 0);
      }
  }

#pragma unroll
  for (int i = 0; i < 2; ++i)
#pragma unroll
    for (int j = 0; j < 2; ++j) {
      int col = bn + nt + j * 16 + lo;
      float bb = bo[col];
#pragma unroll
      for (int r = 0; r < 4; ++r) {
        int row = bm + mt + i * 16 + quad * 4 + r;
        out[(size_t)row * DM + col] = acc[i][j][r] + bb;
      }
    }
}

// ---------------------------------------------------------------------------
extern "C" void kernel_launch(void* const* d_in, const int* in_sizes, int n_in,
                              void* d_out, int out_size, void* d_ws, size_t ws_size,
                              hipStream_t stream) {
  const float* X  = (const float*)d_in[0];
  const float* Wq = (const float*)d_in[1];
  const float* bq = (const float*)d_in[2];
  const float* Wk = (const float*)d_in[3];
  const float* bk = (const float*)d_in[4];
  const float* Wv = (const float*)d_in[5];
  const float* bv = (const float*)d_in[6];
  const float* Wo = (const float*)d_in[7];
  const float* bo = (const float*)d_in[8];
  const float* Pk = (const float*)d_in[9];
  const float* Pv = (const float*)d_in[10];
  float* out = (float*)d_out;

  char* p = (char*)d_ws;
  const size_t szX   = (size_t)Bc * Nseq * DM * 2;          // 4 MB
  const size_t szW   = (size_t)DM * DM * 2;                 // 512 KB
  const size_t szPvt = (size_t)Hh * 64 * PVROWS * 2;        // ~1 MB
  const size_t szQKV = (size_t)Bc * Hh * Nseq * 64 * 2;     // 4 MB
  unsigned short* Xb   = (unsigned short*)p; p += szX;
  unsigned short* Wqt  = (unsigned short*)p; p += szW;
  unsigned short* Wkt  = (unsigned short*)p; p += szW;
  unsigned short* Wvt  = (unsigned short*)p; p += szW;
  unsigned short* Woth = (unsigned short*)p; p += szW;
  unsigned short* Wotl = (unsigned short*)p; p += szW;
  unsigned short* Pvt  = (unsigned short*)p; p += szPvt;
  unsigned short* Qb   = (unsigned short*)p; p += szQKV;
  unsigned short* Kb   = (unsigned short*)p; p += szQKV;
  unsigned short* Vt   = (unsigned short*)p; p += szQKV;
  unsigned short* Awh  = (unsigned short*)p; p += szX;
  unsigned short* Awl  = (unsigned short*)p; p += szX;

  dim3 blk(256);
  prep_cvt<<<dim3(2048), blk, 0, stream>>>(X, Xb);
  pv_trans<<<dim3(17, 8), blk, 0, stream>>>(Pv, Pvt);
  wtrans<<<dim3(16, 16, 5), blk, 0, stream>>>(Wq, Wk, Wv, Wo, Wqt, Wkt, Wvt, Woth, Wotl);
  gemm_qkv<<<dim3(8, 64, 3), blk, 0, stream>>>(Xb, Wqt, Wkt, Wvt, bq, bk, bv, Qb, Kb, Vt);
  attn_fused<<<dim3(Nseq / 16, Hh, Bc), blk, 0, stream>>>(Qb, Kb, Vt, Pk, Pvt, Awh, Awl);
  gemm_final<<<dim3(8, 64), blk, 0, stream>>>(Awh, Awl, Woth, Wotl, bo, out);
}

// Round 5
// 193.807 us; speedup vs baseline: 8.0334x; 1.0819x over previous
//
#include <hip/hip_runtime.h>
#include <math.h>

#define Bc 8
#define Nseq 512
#define DM 512
#define Hh 8
#define NUMREL 1023
#define ZOFF 511   // NUMREL/2
#define PVROWS 1040  // Pvt padded g-extent (>= 496+544, mult of 16)

typedef short bf16x8 __attribute__((ext_vector_type(8)));
typedef float f32x4 __attribute__((ext_vector_type(4)));

__device__ __forceinline__ unsigned short f2bf(float f) {
  unsigned u = __builtin_bit_cast(unsigned, f);
  u += 0x7fff + ((u >> 16) & 1);   // RNE
  return (unsigned short)(u >> 16);
}
__device__ __forceinline__ float bf2f(unsigned short h) {
  unsigned u = ((unsigned)h) << 16;
  return __builtin_bit_cast(float, u);
}

// ---------------------------------------------------------------------------
// prep_cvt: X fp32 -> bf16 (2M elems), float4 vectorized.
// ---------------------------------------------------------------------------
__global__ __launch_bounds__(256) void prep_cvt(const float* __restrict__ X,
                                                unsigned short* __restrict__ Xb) {
  int idx = blockIdx.x * 256 + threadIdx.x;
  float4 v = ((const float4*)X)[idx];
  ushort4 o;
  o.x = f2bf(v.x); o.y = f2bf(v.y); o.z = f2bf(v.z); o.w = f2bf(v.w);
  ((ushort4*)Xb)[idx] = o;
}

// ---------------------------------------------------------------------------
// pv_trans: Pv [1023][8][64] fp32 -> Pvt [8*64][PVROWS] bf16 (g-contiguous,
// zero-padded rows g in [1023, PVROWS)). grid (17, 8).
// ---------------------------------------------------------------------------
__global__ __launch_bounds__(256) void pv_trans(const float* __restrict__ Pv,
                                                unsigned short* __restrict__ Pvt) {
  const int g0 = blockIdx.x * 64, hd0 = blockIdx.y * 64;
  __shared__ float t[64][65];
  const int tid = threadIdx.x;
#pragma unroll
  for (int u = 0; u < 16; ++u) {
    int idx = u * 256 + tid, r = idx >> 6, c = idx & 63;
    int g = g0 + r;
    t[r][c] = g < NUMREL ? Pv[(size_t)g * 512 + hd0 + c] : 0.f;
  }
  __syncthreads();
#pragma unroll
  for (int u = 0; u < 16; ++u) {
    int idx = u * 256 + tid, r = idx >> 6, c = idx & 63;
    int g = g0 + c;
    if (g < PVROWS) Pvt[(size_t)(hd0 + r) * PVROWS + g] = f2bf(t[c][r]);
  }
}

// ---------------------------------------------------------------------------
// wtrans: W[K,N] -> Wt[n][k] bf16. z=0..2: Wq/Wk/Wv; z=3: Wo hi; z=4: Wo lo.
// ---------------------------------------------------------------------------
__global__ __launch_bounds__(256) void wtrans(const float* __restrict__ Wq,
                                              const float* __restrict__ Wk,
                                              const float* __restrict__ Wv,
                                              const float* __restrict__ Wo,
                                              unsigned short* __restrict__ Wqt,
                                              unsigned short* __restrict__ Wkt,
                                              unsigned short* __restrict__ Wvt,
                                              unsigned short* __restrict__ Woth,
                                              unsigned short* __restrict__ Wotl) {
  const int z = blockIdx.z;
  const float* src = z == 0 ? Wq : z == 1 ? Wk : z == 2 ? Wv : Wo;
  unsigned short* dst = z == 0 ? Wqt : z == 1 ? Wkt : z == 2 ? Wvt : z == 3 ? Woth : Wotl;
  const int k0 = blockIdx.y * 32, n0 = blockIdx.x * 32;
  __shared__ float t[32][33];
  const int tid = threadIdx.x;
#pragma unroll
  for (int u = 0; u < 4; ++u) {
    int idx = u * 256 + tid, r = idx >> 5, c = idx & 31;
    t[r][c] = src[(size_t)(k0 + r) * DM + n0 + c];
  }
  __syncthreads();
#pragma unroll
  for (int u = 0; u < 4; ++u) {
    int idx = u * 256 + tid, r = idx >> 5, c = idx & 31;
    float v = t[c][r];
    unsigned short hv = f2bf(v);
    if (z == 4) hv = f2bf(v - bf2f(hv));
    dst[(size_t)(n0 + r) * DM + k0 + c] = hv;
  }
}

// ---------------------------------------------------------------------------
// gemm_qkv: z-FUSED bf16 MFMA, no LDS. One block computes the 64x64 tile of
// Q, K and V (A-fragments reused in registers, 12 MFMA per K-step per wave).
// Explicit ping-pong software pipeline over the fully-unrolled K-loop.
// Outputs: Qb/Kb [(bh)*N+i][64]; Vt [(bh)*64+d][512] (transposed). grid (8,64).
// ---------------------------------------------------------------------------
__global__ __launch_bounds__(256) void gemm_qkv(const unsigned short* __restrict__ Xb,
                                                const unsigned short* __restrict__ Wqt,
                                                const unsigned short* __restrict__ Wkt,
                                                const unsigned short* __restrict__ Wvt,
                                                const float* __restrict__ bq,
                                                const float* __restrict__ bk,
                                                const float* __restrict__ bv,
                                                unsigned short* __restrict__ Qb,
                                                unsigned short* __restrict__ Kb,
                                                unsigned short* __restrict__ Vt) {
  const int bm = blockIdx.y * 64, bn = blockIdx.x * 64;
  const int tid = threadIdx.x, w = tid >> 6, lane = tid & 63;
  const int lo = lane & 15, quad = lane >> 4;
  const int mt = (w >> 1) * 32, nt = (w & 1) * 32;

  const unsigned short* arow0 = Xb + (size_t)(bm + mt + lo) * DM + quad * 8;
  const unsigned short* arow1 = arow0 + 16 * DM;
  const size_t ncol0 = (size_t)(bn + nt + lo) * DM + quad * 8;
  const size_t ncol1 = ncol0 + 16 * DM;

  f32x4 acc[3][2][2] = {};
  bf16x8 af[2][2], bfq[2][2], bfk[2][2], bfv[2][2];

#define LOADK(buf, k0)                                                      \
  do {                                                                      \
    af[buf][0] = *(const bf16x8*)(arow0 + (k0));                            \
    af[buf][1] = *(const bf16x8*)(arow1 + (k0));                            \
    bfq[buf][0] = *(const bf16x8*)(Wqt + ncol0 + (k0));                     \
    bfq[buf][1] = *(const bf16x8*)(Wqt + ncol1 + (k0));                     \
    bfk[buf][0] = *(const bf16x8*)(Wkt + ncol0 + (k0));                     \
    bfk[buf][1] = *(const bf16x8*)(Wkt + ncol1 + (k0));                     \
    bfv[buf][0] = *(const bf16x8*)(Wvt + ncol0 + (k0));                     \
    bfv[buf][1] = *(const bf16x8*)(Wvt + ncol1 + (k0));                     \
  } while (0)

  LOADK(0, 0);
#pragma unroll
  for (int ks = 0; ks < 16; ++ks) {
    const int cur = ks & 1, nxt = cur ^ 1;
    if (ks < 15) LOADK(nxt, (ks + 1) * 32);
#pragma unroll
    for (int i = 0; i < 2; ++i)
#pragma unroll
      for (int j = 0; j < 2; ++j) {
        acc[0][i][j] = __builtin_amdgcn_mfma_f32_16x16x32_bf16(af[cur][i], bfq[cur][j], acc[0][i][j], 0, 0, 0);
        acc[1][i][j] = __builtin_amdgcn_mfma_f32_16x16x32_bf16(af[cur][i], bfk[cur][j], acc[1][i][j], 0, 0, 0);
        acc[2][i][j] = __builtin_amdgcn_mfma_f32_16x16x32_bf16(af[cur][i], bfv[cur][j], acc[2][i][j], 0, 0, 0);
      }
  }
#undef LOADK

#pragma unroll
  for (int z = 0; z < 3; ++z) {
    const float* bias = z == 0 ? bq : z == 1 ? bk : bv;
#pragma unroll
    for (int i = 0; i < 2; ++i)
#pragma unroll
      for (int j = 0; j < 2; ++j) {
        int col = bn + nt + j * 16 + lo;
        int h = col >> 6, d = col & 63;
        float bv_ = bias[col];
#pragma unroll
        for (int r = 0; r < 4; ++r) {
          int row = bm + mt + i * 16 + quad * 4 + r;
          int b = row >> 9, is = row & 511;
          unsigned short val = f2bf(acc[z][i][j][r] + bv_);
          if (z == 2)
            Vt[((size_t)(b * Hh + h) * 64 + d) * 512 + is] = val;
          else if (z == 0)
            Qb[((size_t)(b * Hh + h) * Nseq + is) * 64 + d] = val;
          else
            Kb[((size_t)(b * Hh + h) * Nseq + is) * 64 + d] = val;
        }
      }
  }
}

// ---------------------------------------------------------------------------
// attn_fused: per block = (b, h, 16-row i-tile). Phase 1: QK^T + Pk softmax
// -> P bf16 in LDS (unshifted + shifted). Phase 2: P@V + P'@Pv with B-operands
// loaded DIRECTLY from global (Vt / Pvt, k-contiguous) — no in-loop barriers.
// ---------------------------------------------------------------------------
#define PSV 520  // pstrip row stride (elems): 4*odd -> 2-way aliasing (free)
#define PSH 552  // pshift row stride (elems): 4*odd -> 2-way aliasing (free)

__global__ __launch_bounds__(256) void attn_fused(const unsigned short* __restrict__ Qb,
                                                  const unsigned short* __restrict__ Kb,
                                                  const unsigned short* __restrict__ Vt,
                                                  const float* __restrict__ Pk,
                                                  const unsigned short* __restrict__ Pvt,
                                                  unsigned short* __restrict__ Awh,
                                                  unsigned short* __restrict__ Awl) {
  const int i0 = blockIdx.x * 16;
  const int h = blockIdx.y, b = blockIdx.z;
  const int bh = b * Hh + h;
  const int tid = threadIdx.x;
  const int w = tid >> 6;
  const int lane = tid & 63;
  const int lo = lane & 15, quad = lane >> 4;

  __shared__ __align__(16) unsigned short pstrip[16 * PSV];
  __shared__ __align__(16) unsigned short pshift[16 * PSH];
  __shared__ float pk_lds[544];
  __shared__ float redm[4][16];
  __shared__ float redl[4][16];

  // zero pshift (pads beyond the diagonal band must be 0); pstrip fully written
  int4 z4; z4.x = z4.y = z4.z = z4.w = 0;
  for (int c = tid; c < 16 * PSH / 8; c += 256) ((int4*)pshift)[c] = z4;
  for (int t = tid; t < 527; t += 256)
    pk_lds[t] = Pk[(size_t)(ZOFF - i0 - 15 + t) * Hh + h];
  __syncthreads();

  // ---------------- Phase 1: scores + softmax ----------------
  const unsigned short* qbase = Qb + ((size_t)bh * Nseq + i0 + lo) * 64;
  bf16x8 qa0 = *(const bf16x8*)(qbase + quad * 8);
  bf16x8 qa1 = *(const bf16x8*)(qbase + 32 + quad * 8);

  const int jw = w * 128;
  float sv[8][4];
  float mrow[4] = {-1e30f, -1e30f, -1e30f, -1e30f};
#pragma unroll
  for (int s = 0; s < 8; ++s) {
    const unsigned short* kbase = Kb + ((size_t)bh * Nseq + jw + s * 16 + lo) * 64;
    bf16x8 kb0 = *(const bf16x8*)(kbase + quad * 8);
    bf16x8 kb1 = *(const bf16x8*)(kbase + 32 + quad * 8);
    f32x4 c = {0.f, 0.f, 0.f, 0.f};
    c = __builtin_amdgcn_mfma_f32_16x16x32_bf16(qa0, kb0, c, 0, 0, 0);
    c = __builtin_amdgcn_mfma_f32_16x16x32_bf16(qa1, kb1, c, 0, 0, 0);
    int j = jw + s * 16 + lo;
#pragma unroll
    for (int r = 0; r < 4; ++r) {
      int rl = quad * 4 + r;
      float v = (c[r] + pk_lds[j - rl + 15]) * 0.125f;
      sv[s][r] = v;
      mrow[r] = fmaxf(mrow[r], v);
    }
  }
#pragma unroll
  for (int m = 1; m <= 8; m <<= 1)
#pragma unroll
    for (int r = 0; r < 4; ++r) mrow[r] = fmaxf(mrow[r], __shfl_xor(mrow[r], m));
  if (lo == 0)
#pragma unroll
    for (int r = 0; r < 4; ++r) redm[w][quad * 4 + r] = mrow[r];
  __syncthreads();
  float mfin[4];
#pragma unroll
  for (int r = 0; r < 4; ++r) {
    int rl = quad * 4 + r;
    mfin[r] = fmaxf(fmaxf(redm[0][rl], redm[1][rl]), fmaxf(redm[2][rl], redm[3][rl]));
  }
  float lrow[4] = {0.f, 0.f, 0.f, 0.f};
#pragma unroll
  for (int s = 0; s < 8; ++s)
#pragma unroll
    for (int r = 0; r < 4; ++r) {
      float e = __expf(sv[s][r] - mfin[r]);
      sv[s][r] = e;
      lrow[r] += e;
    }
#pragma unroll
  for (int m = 1; m <= 8; m <<= 1)
#pragma unroll
    for (int r = 0; r < 4; ++r) lrow[r] += __shfl_xor(lrow[r], m);
  if (lo == 0)
#pragma unroll
    for (int r = 0; r < 4; ++r) redl[w][quad * 4 + r] = lrow[r];
  __syncthreads();
#pragma unroll
  for (int r = 0; r < 4; ++r) {
    int rl = quad * 4 + r;
    float linv = 1.f / (redl[0][rl] + redl[1][rl] + redl[2][rl] + redl[3][rl]);
#pragma unroll
    for (int s = 0; s < 8; ++s) {
      int j = jw + s * 16 + lo;
      unsigned short pb = f2bf(sv[s][r] * linv);
      pstrip[rl * PSV + j] = pb;
      pshift[rl * PSH + j - rl + 15] = pb;
    }
  }
  __syncthreads();

  // ---------------- Phase 2: P@V + P'@Pv (no barriers) ----------------
  f32x4 oacc = {0.f, 0.f, 0.f, 0.f};
  const int d = w * 16 + lo;

  const unsigned short* vrow = Vt + ((size_t)bh * 64 + d) * 512;
#pragma unroll 4
  for (int ks = 0; ks < 16; ++ks) {
    bf16x8 pa = *(const bf16x8*)(pstrip + lo * PSV + ks * 32 + quad * 8);
    bf16x8 vb = *(const bf16x8*)(vrow + ks * 32 + quad * 8);
    oacc = __builtin_amdgcn_mfma_f32_16x16x32_bf16(pa, vb, oacc, 0, 0, 0);
  }

  const int tminrow = ZOFF - i0 - 15;  // multiple of 16, >= 0
  const unsigned short* pvrow = Pvt + ((size_t)h * 64 + d) * PVROWS + tminrow;
#pragma unroll 4
  for (int ks = 0; ks < 17; ++ks) {
    bf16x8 pa = *(const bf16x8*)(pshift + lo * PSH + ks * 32 + quad * 8);
    bf16x8 vb = *(const bf16x8*)(pvrow + ks * 32 + quad * 8);
    oacc = __builtin_amdgcn_mfma_f32_16x16x32_bf16(pa, vb, oacc, 0, 0, 0);
  }

  // write Aw hi/lo bf16, layout [b*N+i][H*64]
#pragma unroll
  for (int r = 0; r < 4; ++r) {
    int i = i0 + quad * 4 + r;
    float o = oacc[r];
    unsigned short hi = f2bf(o);
    unsigned short lov = f2bf(o - bf2f(hi));
    size_t off = ((size_t)(b * Nseq + i)) * (Hh * 64) + h * 64 + d;
    Awh[off] = hi;
    Awl[off] = lov;
  }
}

// ---------------------------------------------------------------------------
// gemm_final: split-bf16 (3-term) MFMA GEMM. out = Ah@Bh + Ah@Bl + Al@Bh + bo
// ---------------------------------------------------------------------------
__global__ __launch_bounds__(256) void gemm_final(const unsigned short* __restrict__ Ah,
                                                  const unsigned short* __restrict__ Al,
                                                  const unsigned short* __restrict__ Bh,
                                                  const unsigned short* __restrict__ Bl,
                                                  const float* __restrict__ bo,
                                                  float* __restrict__ out) {
  const int bm = blockIdx.y * 64, bn = blockIdx.x * 64;
  const int tid = threadIdx.x, w = tid >> 6, lane = tid & 63;
  const int lo = lane & 15, quad = lane >> 4;
  const int mt = (w >> 1) * 32, nt = (w & 1) * 32;

  const size_t arow0 = (size_t)(bm + mt + lo) * DM + quad * 8;
  const size_t arow1 = arow0 + 16 * DM;
  const size_t ncol0 = (size_t)(bn + nt + lo) * DM + quad * 8;
  const size_t ncol1 = ncol0 + 16 * DM;

  f32x4 acc[2][2] = {};
  bf16x8 ah[2][2], al[2][2], bh[2][2], bl[2][2];

#define LOADK2(buf, k0)                                       \
  do {                                                        \
    ah[buf][0] = *(const bf16x8*)(Ah + arow0 + (k0));         \
    ah[buf][1] = *(const bf16x8*)(Ah + arow1 + (k0));         \
    al[buf][0] = *(const bf16x8*)(Al + arow0 + (k0));         \
    al[buf][1] = *(const bf16x8*)(Al + arow1 + (k0));         \
    bh[buf][0] = *(const bf16x8*)(Bh + ncol0 + (k0));         \
    bh[buf][1] = *(const bf16x8*)(Bh + ncol1 + (k0));         \
    bl[buf][0] = *(const bf16x8*)(Bl + ncol0 + (k0));         \
    bl[buf][1] = *(const bf16x8*)(Bl + ncol1 + (k0));         \
  } while (0)

  LOADK2(0, 0);
#pragma unroll
  for (int ks = 0; ks < 16; ++ks) {
    const int cur = ks & 1, nxt = cur ^ 1;
    if (ks < 15) LOADK2(nxt, (ks + 1) * 32);
#pragma unroll
    for (int i = 0; i < 2; ++i)
#pragma unroll
      for (int j = 0; j < 2; ++j) {
        acc[i][j] = __builtin_amdgcn_mfma_f32_16x16x32_bf16(ah[cur][i], bh[cur][j], acc[i][j], 0, 0, 0);
        acc[i][j] = __builtin_amdgcn_mfma_f32_16x16x32_bf16(ah[cur][i], bl[cur][j], acc[i][j], 0, 0, 0);
        acc[i][j] = __builtin_amdgcn_mfma_f32_16x16x32_bf16(al[cur][i], bh[cur][j], acc[i][j], 0, 0, 0);
      }
  }
#undef LOADK2

#pragma unroll
  for (int i = 0; i < 2; ++i)
#pragma unroll
    for (int j = 0; j < 2; ++j) {
      int col = bn + nt + j * 16 + lo;
      float bb = bo[col];
#pragma unroll
      for (int r = 0; r < 4; ++r) {
        int row = bm + mt + i * 16 + quad * 4 + r;
        out[(size_t)row * DM + col] = acc[i][j][r] + bb;
      }
    }
}

// ---------------------------------------------------------------------------
extern "C" void kernel_launch(void* const* d_in, const int* in_sizes, int n_in,
                              void* d_out, int out_size, void* d_ws, size_t ws_size,
                              hipStream_t stream) {
  const float* X  = (const float*)d_in[0];
  const float* Wq = (const float*)d_in[1];
  const float* bq = (const float*)d_in[2];
  const float* Wk = (const float*)d_in[3];
  const float* bk = (const float*)d_in[4];
  const float* Wv = (const float*)d_in[5];
  const float* bv = (const float*)d_in[6];
  const float* Wo = (const float*)d_in[7];
  const float* bo = (const float*)d_in[8];
  const float* Pk = (const float*)d_in[9];
  const float* Pv = (const float*)d_in[10];
  float* out = (float*)d_out;

  char* p = (char*)d_ws;
  const size_t szX   = (size_t)Bc * Nseq * DM * 2;          // 4 MB
  const size_t szW   = (size_t)DM * DM * 2;                 // 512 KB
  const size_t szPvt = (size_t)Hh * 64 * PVROWS * 2;        // ~1 MB
  const size_t szQKV = (size_t)Bc * Hh * Nseq * 64 * 2;     // 4 MB
  unsigned short* Xb   = (unsigned short*)p; p += szX;
  unsigned short* Wqt  = (unsigned short*)p; p += szW;
  unsigned short* Wkt  = (unsigned short*)p; p += szW;
  unsigned short* Wvt  = (unsigned short*)p; p += szW;
  unsigned short* Woth = (unsigned short*)p; p += szW;
  unsigned short* Wotl = (unsigned short*)p; p += szW;
  unsigned short* Pvt  = (unsigned short*)p; p += szPvt;
  unsigned short* Qb   = (unsigned short*)p; p += szQKV;
  unsigned short* Kb   = (unsigned short*)p; p += szQKV;
  unsigned short* Vt   = (unsigned short*)p; p += szQKV;
  unsigned short* Awh  = (unsigned short*)p; p += szX;
  unsigned short* Awl  = (unsigned short*)p; p += szX;

  dim3 blk(256);
  prep_cvt<<<dim3(2048), blk, 0, stream>>>(X, Xb);
  pv_trans<<<dim3(17, 8), blk, 0, stream>>>(Pv, Pvt);
  wtrans<<<dim3(16, 16, 5), blk, 0, stream>>>(Wq, Wk, Wv, Wo, Wqt, Wkt, Wvt, Woth, Wotl);
  gemm_qkv<<<dim3(8, 64), blk, 0, stream>>>(Xb, Wqt, Wkt, Wvt, bq, bk, bv, Qb, Kb, Vt);
  attn_fused<<<dim3(Nseq / 16, Hh, Bc), blk, 0, stream>>>(Qb, Kb, Vt, Pk, Pvt, Awh, Awl);
  gemm_final<<<dim3(8, 64), blk, 0, stream>>>(Awh, Awl, Woth, Wotl, bo, out);
}